// Round 6
// baseline (561.754 us; speedup 1.0000x reference)
//
#include <hip/hip_runtime.h>
#include <stdint.h>

// B=8, T=4096, C=1024, NH=64, HD=16. M = B*T = 32768.

typedef __attribute__((ext_vector_type(8))) __bf16 bf16x8;
typedef __attribute__((ext_vector_type(4))) float f32x4;
typedef __attribute__((ext_vector_type(4))) unsigned int u32x4;
typedef __attribute__((ext_vector_type(4))) unsigned short u16x4;

#define AS1 __attribute__((address_space(1)))
#define AS3 __attribute__((address_space(3)))

__device__ __forceinline__ unsigned short f2bf(float f) {
  unsigned int u = __builtin_bit_cast(unsigned int, f);
  u += 0x7FFFu + ((u >> 16) & 1u);
  return (unsigned short)(u >> 16);
}

__device__ __forceinline__ void gl_lds16(const unsigned short* g, unsigned short* l) {
  __builtin_amdgcn_global_load_lds((const AS1 unsigned int*)g, (AS3 unsigned int*)l, 16, 0, 0);
}

// ---------------- fp32 -> bf16 converts ----------------
__global__ __launch_bounds__(256)
void cvt_x(const float* __restrict__ src, unsigned short* __restrict__ dst, int n4) {
  int i = blockIdx.x * blockDim.x + threadIdx.x;
  const int stride = gridDim.x * blockDim.x;
  for (; i < n4; i += stride) {
    f32x4 v = *(const f32x4*)(src + (size_t)i * 4);
    u16x4 o;
    o.x = f2bf(v.x); o.y = f2bf(v.y); o.z = f2bf(v.z); o.w = f2bf(v.w);
    *(u16x4*)(dst + (size_t)i * 4) = o;
  }
}

// Repack all four 1024x1024 weights into MFMA-fragment order (r4-validated):
// per weight, block f = n16*32 + ks32 (1KB each); lane l holds
// W[n16*16 + (l&15)][ks32*32 + (l>>4)*8 .. +8].
__global__ __launch_bounds__(256)
void cvt_w(const float* __restrict__ w0, const float* __restrict__ w1,
           const float* __restrict__ w2, const float* __restrict__ w3,
           unsigned short* __restrict__ dst) {
  const int g = blockIdx.x * 256 + threadIdx.x;   // 0..524287
  const int w = g >> 17;
  const int r = g & 131071;
  const int f = r >> 6;                           // n16*32 + ks32
  const int l = r & 63;
  const int n = (f >> 5) * 16 + (l & 15);
  const int k = (f & 31) * 32 + (l >> 4) * 8;
  const float* ws[4] = {w0, w1, w2, w3};
  const float* src = ws[w] + (size_t)n * 1024 + k;
  f32x4 v0 = *(const f32x4*)src;
  f32x4 v1 = *(const f32x4*)(src + 4);
  u16x4 a, b;
  a.x = f2bf(v0.x); a.y = f2bf(v0.y); a.z = f2bf(v0.z); a.w = f2bf(v0.w);
  b.x = f2bf(v1.x); b.y = f2bf(v1.y); b.z = f2bf(v1.z); b.w = f2bf(v1.w);
  unsigned short* o = dst + (size_t)g * 8;
  *(u16x4*)o = a;
  *(u16x4*)(o + 4) = b;
}

// =======================================================================
// 256x256-tile bf16 GEMM: A staged in LDS (64KB dbuf), B from L2 to regs.
// out[m][n] = sum_k A[m][k] * W[n][k] + bias[n]
// KIND 0: fused QKV (N=3072), KIND 1: proj (N=1024, fp32 out)
//
// 8 waves = 2(M) x 4(N); per-wave C = 128x64 (acc[8][4] f32x4 = 128 regs).
// K-tile = 64. Per K-tile, 4 quadrants q=0..3 (MFMA over local n16=q).
// Per quadrant each wave issues: 1 gl_lds (A-stage for tile t+1, after the
// tile barrier) + 2 global B-frag loads (for quadrant q+1) + 16 MFMA.
// Quadrant 0 additionally reads the full A-tile frags (16 ds_read_b128).
//
// Sync audit (ONE barrier + ONE vmcnt(0) per K-tile):
//  RAW(LDS): stages for tile t issued at t-1.q0..q3; each wave drains its
//   own with vmcnt(0) before the t.q0 barrier; barrier -> all waves' stages
//   visible before any wave's q0 ds_reads (issued after the barrier).
//  WAR(LDS): stages into buf b for tile t+1 are issued only after the t.q0
//   barrier; a wave reaches that barrier only after finishing t-1.q0's
//   ds_reads of buf b (program order) -> no overwrite of live reads.
//  B/aF data deps: plain loads -> compiler inserts fine-grained counted
//   vmcnt/lgkmcnt (better than manual drains).
// =======================================================================

#define MFMA16(Q, BR) do {                                                   \
  __builtin_amdgcn_s_setprio(1);                                             \
  _Pragma("unroll")                                                          \
  for (int mi = 0; mi < 8; ++mi) {                                           \
    acc[mi][Q] = __builtin_amdgcn_mfma_f32_16x16x32_bf16(aF[mi][0], BR[0], acc[mi][Q], 0, 0, 0); \
    acc[mi][Q] = __builtin_amdgcn_mfma_f32_16x16x32_bf16(aF[mi][1], BR[1], acc[mi][Q], 0, 0, 0); \
  }                                                                          \
  __builtin_amdgcn_s_setprio(0);                                             \
} while (0)

template<int KIND>
__global__ __launch_bounds__(512, 2)
void gemm256(const unsigned short* __restrict__ A,
             const unsigned short* __restrict__ Wf,
             const float* __restrict__ b0, const float* __restrict__ b1,
             const float* __restrict__ b2,
             unsigned short* __restrict__ oq, unsigned short* __restrict__ okT,
             unsigned short* __restrict__ ovT, float* __restrict__ of)
{
  __shared__ __align__(16) unsigned short lds[32768];   // 2 bufs x 256x64 bf16 = 64KB

  const int tid  = threadIdx.x;
  const int lane = tid & 63;
  const int wid  = tid >> 6;          // 0..7
  const int wm   = wid >> 2;          // 0..1 (M)
  const int wn   = wid & 3;           // 0..3 (N)
  const int fr   = lane & 15;
  const int fg   = lane >> 4;

  // XCD-bijective, L2-chunked block order (r5-validated).
  const int flat = blockIdx.x;
  const int xcd  = flat & 7;
  const int vid  = flat >> 3;
  int brow_t, bcol_t;
  if (KIND == 0) {                    // 1536 blocks: per XCD 192 = 4cg x 4pg x 4p x 3c
    const int cg = vid / 48, r1 = vid % 48;
    const int pg = r1 / 12, r2 = r1 % 12;
    brow_t = xcd * 16 + pg * 4 + r2 / 3;
    bcol_t = cg * 3 + r2 % 3;
  } else {                            // 512 blocks: per XCD 64 = 4pg x 4p x 4c
    const int pg = vid >> 4, r1 = vid & 15;
    brow_t = xcd * 16 + pg * 4 + (r1 >> 2);
    bcol_t = r1 & 3;
  }
  const int brow = brow_t * 256;
  const int bcol = bcol_t * 256;

  // A staging: wave w, op s covers rows w*32 + s*8 + (lane>>3), 64 k each.
  // LDS dst linear: offset = row*128B + (lane&7)*16B = base + lane*16 (HW pattern).
  // Stored 16B-slot (lane&7) holds global k-block (lane&7) ^ (row&7).
  const int scol = (((lane & 7) ^ ((lane >> 3) & 7)) << 3);
  const unsigned short* a_src = A + (size_t)(brow + wid * 32 + (lane >> 3)) * 1024 + scol;
  unsigned short* a_dst = lds + wid * 2048 + (lane & 0) /*uniform*/;

  auto stA = [&](int kt, int buf, int s) {
    gl_lds16(a_src + (size_t)s * 8192 + kt * 64,
             lds + buf * 16384 + (wid * 4 + s) * 512);
  };

  // A-frag ds_read: frag(mi, ks): row = wm*128 + mi*16 + fr,
  // stored slot = (ks*4 + fg) ^ (fr&7)  (row&7 == fr&7).
  const char* aP = (const char*)lds + (size_t)(wm * 128 + fr) * 128;
  const int sl0 = ((fg ^ (fr & 7)) << 4);
  const int sl1 = (((4 | fg) ^ (fr & 7)) << 4);

  // B frag-packed pointer: global n16 base = (bcol + wn*64)>>4; frag(ni,ks32)
  // at (n16g*32 + ks32)*512 shorts, 16B per lane.
  const unsigned short* wfp = Wf + (size_t)((bcol + wn * 64) >> 4) * 32 * 512 + lane * 8;
  auto loadB = [&](int kt, int ni, bf16x8 (&d)[2]) {
    d[0] = __builtin_bit_cast(bf16x8, *(const u32x4*)(wfp + (size_t)(ni * 32 + kt * 2) * 512));
    d[1] = __builtin_bit_cast(bf16x8, *(const u32x4*)(wfp + (size_t)(ni * 32 + kt * 2 + 1) * 512));
  };

  const f32x4 fz = {0.f, 0.f, 0.f, 0.f};
  f32x4 acc[8][4];
  #pragma unroll
  for (int mi = 0; mi < 8; ++mi)
    #pragma unroll
    for (int ni = 0; ni < 4; ++ni) acc[mi][ni] = fz;

  bf16x8 aF[8][2];
  bf16x8 bEven[2], bOdd[2];

  // prologue: stage tile 0 into buf 0; preload B(t0, q0).
  stA(0, 0, 0); stA(0, 0, 1); stA(0, 0, 2); stA(0, 0, 3);
  loadB(0, 0, bEven);

  for (int t = 0; t < 16; ++t) {
    const bool nl = (t < 15);
    const int nb = (t + 1) & 1;
    const int bufB = (t & 1) * 32768;   // byte offset of current A buffer

    // ---- tile barrier: own stages drained, then cross-wave visibility ----
    asm volatile("s_waitcnt vmcnt(0)" ::: "memory");
    __builtin_amdgcn_sched_barrier(0);
    __builtin_amdgcn_s_barrier();
    __builtin_amdgcn_sched_barrier(0);

    // ---- q0 ----
    if (nl) stA(t + 1, nb, 0);
    loadB(t, 1, bOdd);
    #pragma unroll
    for (int mi = 0; mi < 8; ++mi) {
      aF[mi][0] = __builtin_bit_cast(bf16x8, *(const u32x4*)(aP + bufB + mi * 2048 + sl0));
      aF[mi][1] = __builtin_bit_cast(bf16x8, *(const u32x4*)(aP + bufB + mi * 2048 + sl1));
    }
    MFMA16(0, bEven);
    // ---- q1 ----
    if (nl) stA(t + 1, nb, 1);
    loadB(t, 2, bEven);
    MFMA16(1, bOdd);
    // ---- q2 ----
    if (nl) stA(t + 1, nb, 2);
    loadB(t, 3, bOdd);
    MFMA16(2, bEven);
    // ---- q3 ----
    if (nl) { stA(t + 1, nb, 3); loadB(t + 1, 0, bEven); }
    MFMA16(3, bOdd);
  }

  // ---------------- epilogue ----------------
  const int sec = (KIND == 0) ? (bcol >> 10) : 0;
  const float* bias = (KIND == 1) ? b0 : (sec == 0 ? b0 : (sec == 1 ? b1 : b2));

  #pragma unroll
  for (int ni = 0; ni < 4; ++ni) {
    const int n_glob = bcol + wn * 64 + ni * 16 + fr;
    const int nn = (KIND == 0) ? (n_glob & 1023) : n_glob;
    const float bv = bias[nn];
    #pragma unroll
    for (int mi = 0; mi < 8; ++mi) {
      const int m0 = brow + wm * 128 + mi * 16 + fg * 4;
      float vals[4];
      #pragma unroll
      for (int r2 = 0; r2 < 4; ++r2) vals[r2] = acc[mi][ni][r2] + bv;

      if (KIND == 0 && sec <= 1) {
        // softmax over the 16 columns (one head's HD) of this fragment
        #pragma unroll
        for (int r2 = 0; r2 < 4; ++r2) {
          float x = vals[r2];
          float mx = x;
          #pragma unroll
          for (int s = 1; s < 16; s <<= 1) mx = fmaxf(mx, __shfl_xor(mx, s, 64));
          float e = __expf(x - mx);
          float sm = e;
          #pragma unroll
          for (int s = 1; s < 16; s <<= 1) sm += __shfl_xor(sm, s, 64);
          vals[r2] = e / sm;
        }
      }

      if (KIND == 1) {
        #pragma unroll
        for (int r2 = 0; r2 < 4; ++r2)
          of[(size_t)(m0 + r2) * 1024 + n_glob] = vals[r2];
      } else if (sec == 0) {
        #pragma unroll
        for (int r2 = 0; r2 < 4; ++r2)
          oq[(size_t)(m0 + r2) * 1024 + nn] = f2bf(vals[r2]);
      } else {
        // transposed per head: dst[((b*64+h)*16+d)*4096 + t]
        unsigned short* o = (sec == 1) ? okT : ovT;
        const int bb = m0 >> 12;
        const int t0 = m0 & 4095;
        const int hh = nn >> 4;
        const int dd = nn & 15;
        u16x4 pk;
        pk.x = f2bf(vals[0]); pk.y = f2bf(vals[1]);
        pk.z = f2bf(vals[2]); pk.w = f2bf(vals[3]);
        *(u16x4*)&o[(((size_t)bb * 64 + hh) * 16 + dd) * 4096 + t0] = pk;
      }
    }
  }
}

// ---------------- per-head linear-attention middle ----------------
__global__ __launch_bounds__(256)
void attn_kernel(const unsigned short* __restrict__ qb,
                 const unsigned short* __restrict__ kT,
                 const unsigned short* __restrict__ vT,
                 unsigned short* __restrict__ yb)
{
  const int head = blockIdx.x;           // b*64 + h
  const int tid  = threadIdx.x;
  const int lane = tid & 63;
  const int wid  = tid >> 6;
  const int fr   = lane & 15;
  const int fg   = lane >> 4;

  const unsigned short* kTh = kT + (size_t)head * 16 * 4096;
  const unsigned short* vTh = vT + (size_t)head * 16 * 4096;

  const u32x4 uz = {0u, 0u, 0u, 0u};
  const f32x4 fz = {0.f, 0.f, 0.f, 0.f};
  const u32x4 uo = {0x3F803F80u, 0x3F803F80u, 0x3F803F80u, 0x3F803F80u};
  const bf16x8 ones = __builtin_bit_cast(bf16x8, uo);

  f32x4 cctx = fz, ckc = fz;
  #pragma unroll 4
  for (int t0 = wid * 1024; t0 < (wid + 1) * 1024; t0 += 32) {
    bf16x8 ak = __builtin_bit_cast(bf16x8, *(const u32x4*)&kTh[(size_t)fr * 4096 + t0 + fg * 8]);
    bf16x8 bv = __builtin_bit_cast(bf16x8, *(const u32x4*)&vTh[(size_t)fr * 4096 + t0 + fg * 8]);
    cctx = __builtin_amdgcn_mfma_f32_16x16x32_bf16(ak, bv, cctx, 0, 0, 0);
    ckc  = __builtin_amdgcn_mfma_f32_16x16x32_bf16(ak, ones, ckc, 0, 0, 0);
  }

  __shared__ float red[4][16][16];
  __shared__ float kcr[4][16];
  __shared__ float ctxf[16][16];
  __shared__ float kcf[16];

  #pragma unroll
  for (int r = 0; r < 4; ++r) red[wid][fg * 4 + r][fr] = cctx[r];
  if (fr == 0) {
    #pragma unroll
    for (int r = 0; r < 4; ++r) kcr[wid][fg * 4 + r] = ckc[r];
  }
  __syncthreads();
  {
    const int d = tid >> 4, e = tid & 15;
    ctxf[d][e] = red[0][d][e] + red[1][d][e] + red[2][d][e] + red[3][d][e];
    if (tid < 16) kcf[tid] = kcr[0][tid] + kcr[1][tid] + kcr[2][tid] + kcr[3][tid];
  }
  __syncthreads();

  bf16x8 bctx = __builtin_bit_cast(bf16x8, uz);
  bf16x8 bkc  = __builtin_bit_cast(bf16x8, uz);
  if (fg < 2) {
    #pragma unroll
    for (int j = 0; j < 8; ++j) {
      const int d = fg * 8 + j;
      bctx[j] = (__bf16)ctxf[d][fr];
      bkc[j]  = (__bf16)kcf[d];
    }
  }

  const int b = head >> 6;
  const int h = head & 63;
  const size_t qbase = (size_t)b * 4096 * 1024 + (size_t)h * 16;

  for (int step = 0; step < 64; ++step) {
    const int t0 = step * 64 + wid * 16;
    bf16x8 af = __builtin_bit_cast(bf16x8, uz);
    if (fg < 2)
      af = __builtin_bit_cast(bf16x8, *(const u32x4*)&qb[qbase + (size_t)(t0 + fr) * 1024 + fg * 8]);
    f32x4 cy = __builtin_amdgcn_mfma_f32_16x16x32_bf16(af, bctx, fz, 0, 0, 0);
    f32x4 cd = __builtin_amdgcn_mfma_f32_16x16x32_bf16(af, bkc,  fz, 0, 0, 0);
    #pragma unroll
    for (int r = 0; r < 4; ++r) {
      const int t = t0 + fg * 4 + r;
      const float yv = cy[r] * __builtin_amdgcn_rcpf(cd[r]);
      yb[qbase + (size_t)t * 1024 + fr] = f2bf(yv);
    }
  }
}

// ---------------- launch ----------------
extern "C" void kernel_launch(void* const* d_in, const int* in_sizes, int n_in,
                              void* d_out, int out_size, void* d_ws, size_t ws_size,
                              hipStream_t stream)
{
  (void)in_sizes; (void)n_in; (void)out_size; (void)ws_size;
  const float* x  = (const float*)d_in[0];
  const float* Wq = (const float*)d_in[1];
  const float* bq = (const float*)d_in[2];
  const float* Wk = (const float*)d_in[3];
  const float* bk = (const float*)d_in[4];
  const float* Wv = (const float*)d_in[5];
  const float* bv = (const float*)d_in[6];
  const float* Wp = (const float*)d_in[7];
  const float* bp = (const float*)d_in[8];

  char* ws = (char*)d_ws;
  // requires ws_size >= 276,824,064 bytes
  unsigned short* xb  = (unsigned short*)(ws);              // 67108864 B; reused as yb
  unsigned short* wb  = (unsigned short*)(ws + 67108864);   // 4 x 2097152 B, frag-packed
  unsigned short* qb  = (unsigned short*)(ws + 75497472);   // 67108864 B
  unsigned short* kTb = (unsigned short*)(ws + 142606336);  // 67108864 B
  unsigned short* vTb = (unsigned short*)(ws + 209715200);  // 67108864 B

  cvt_x<<<2048, 256, 0, stream>>>(x, xb, 33554432 / 4);
  cvt_w<<<2048, 256, 0, stream>>>(Wq, Wk, Wv, Wp, wb);

  gemm256<0><<<1536, 512, 0, stream>>>(xb, wb, bq, bk, bv, qb, kTb, vTb, nullptr);

  attn_kernel<<<512, 256, 0, stream>>>(qb, kTb, vTb, xb /* = yb */);

  gemm256<1><<<512, 512, 0, stream>>>(xb /* yb */, wb + 3145728, bp, bp, bp,
                                      nullptr, nullptr, nullptr, (float*)d_out);
}